// Round 1
// baseline (16917.189 us; speedup 1.0000x reference)
//
#include <hip/hip_runtime.h>
#include <math.h>

#define NN 1000000
#define FF 5

// ---- degree: count in-edges per node (self-loop added later as +1) ----
__global__ void k_deg(const int* __restrict__ ei, int E, unsigned int* __restrict__ deg) {
    int t = blockIdx.x * blockDim.x + threadIdx.x;
    int stride = gridDim.x * blockDim.x;
    for (int e = t; e < E; e += stride) {
        int d = ei[E + e];   // dst half
        atomicAdd(&deg[d], 1u);
    }
}

// ---- dis[i] = rsqrt(deg[i] + 1) ----
__global__ void k_dis(const unsigned int* __restrict__ deg, float* __restrict__ dis) {
    int i = blockIdx.x * blockDim.x + threadIdx.x;
    if (i < NN) dis[i] = rsqrtf((float)(deg[i] + 1u));
}

// ---- layer-1 init: y = (x @ W1) * dis ; z = y (self-loop term) ----
__global__ void k_y1(const float* __restrict__ x, const float* __restrict__ dis,
                     const float* __restrict__ W,
                     float* __restrict__ y, float* __restrict__ z) {
    int i = blockIdx.x * blockDim.x + threadIdx.x;
    if (i >= NN) return;
    float xi[FF];
#pragma unroll
    for (int f = 0; f < FF; f++) xi[f] = x[i * FF + f];
    float d = dis[i];
#pragma unroll
    for (int o = 0; o < FF; o++) {
        float acc = 0.f;
#pragma unroll
        for (int k = 0; k < FF; k++) acc += xi[k] * W[k * FF + o];
        acc *= d;
        y[i * FF + o] = acc;
        z[i * FF + o] = acc;
    }
}

// ---- edge pass: z[dst] += y[src]  (norm factors already folded into y / epilogue) ----
__global__ void k_edge(const int* __restrict__ ei, int E,
                       const float* __restrict__ y, float* __restrict__ z) {
    int t = blockIdx.x * blockDim.x + threadIdx.x;
    int stride = gridDim.x * blockDim.x;
    for (int e = t; e < E; e += stride) {
        int s = ei[e];
        int d = ei[E + e];
        const float* ys = y + (size_t)s * FF;
        float* zd = z + (size_t)d * FF;
#pragma unroll
        for (int f = 0; f < FF; f++) atomicAdd(&zd[f], ys[f]);
    }
}

// ---- between layers: h = relu(z1*dis + b1); y2 = (h @ W2) * dis; z2 = y2 ----
__global__ void k_mid(const float* __restrict__ z1, const float* __restrict__ dis,
                      const float* __restrict__ b1, const float* __restrict__ W2,
                      float* __restrict__ y2, float* __restrict__ z2) {
    int i = blockIdx.x * blockDim.x + threadIdx.x;
    if (i >= NN) return;
    float d = dis[i];
    float h[FF];
#pragma unroll
    for (int f = 0; f < FF; f++) h[f] = fmaxf(z1[i * FF + f] * d + b1[f], 0.f);
#pragma unroll
    for (int o = 0; o < FF; o++) {
        float acc = 0.f;
#pragma unroll
        for (int k = 0; k < FF; k++) acc += h[k] * W2[k * FF + o];
        acc *= d;
        y2[i * FF + o] = acc;
        z2[i * FF + o] = acc;
    }
}

// ---- epilogue: out = relu(z2*dis + b2) @ Wl + bl ----
__global__ void k_final(const float* __restrict__ z2, const float* __restrict__ dis,
                        const float* __restrict__ b2, const float* __restrict__ Wl,
                        const float* __restrict__ bl, float* __restrict__ out) {
    int i = blockIdx.x * blockDim.x + threadIdx.x;
    if (i >= NN) return;
    float d = dis[i];
    float acc = bl[0];
#pragma unroll
    for (int f = 0; f < FF; f++) {
        float h = fmaxf(z2[i * FF + f] * d + b2[f], 0.f);
        acc += h * Wl[f];
    }
    out[i] = acc;
}

extern "C" void kernel_launch(void* const* d_in, const int* in_sizes, int n_in,
                              void* d_out, int out_size, void* d_ws, size_t ws_size,
                              hipStream_t stream) {
    const float* x  = (const float*)d_in[0];
    const int*   ei = (const int*)d_in[1];
    const float* W1 = (const float*)d_in[2];
    const float* b1 = (const float*)d_in[3];
    const float* W2 = (const float*)d_in[4];
    const float* b2 = (const float*)d_in[5];
    const float* Wl = (const float*)d_in[6];
    const float* bl = (const float*)d_in[7];
    float* out = (float*)d_out;
    const int E = in_sizes[1] / 2;   // 32,000,000

    // workspace layout (needs 68 MB)
    char* ws = (char*)d_ws;
    unsigned int* deg = (unsigned int*)(ws);                       // 4 MB
    float* dis = (float*)(ws + (size_t)4 * 1024 * 1024);           // 4 MB
    float* A   = (float*)(ws + (size_t)8 * 1024 * 1024);           // 20 MB (y)
    float* B   = (float*)(ws + (size_t)28 * 1024 * 1024);          // 20 MB (z1)
    float* C   = (float*)(ws + (size_t)48 * 1024 * 1024);          // 20 MB (z2)

    hipMemsetAsync(deg, 0, (size_t)NN * sizeof(unsigned int), stream);

    const int ET = 256, EB = 2048;           // grid-stride edge kernels
    const int NT = 256, NB = (NN + NT - 1) / NT;

    k_deg  <<<EB, ET, 0, stream>>>(ei, E, deg);
    k_dis  <<<NB, NT, 0, stream>>>(deg, dis);
    k_y1   <<<NB, NT, 0, stream>>>(x, dis, W1, A, B);
    k_edge <<<EB, ET, 0, stream>>>(ei, E, A, B);
    k_mid  <<<NB, NT, 0, stream>>>(B, dis, b1, W2, A, C);
    k_edge <<<EB, ET, 0, stream>>>(ei, E, A, C);
    k_final<<<NB, NT, 0, stream>>>(C, dis, b2, Wl, bl, out);
}

// Round 2
// 2411.595 us; speedup vs baseline: 7.0149x; 7.0149x over previous
//
#include <hip/hip_runtime.h>
#include <math.h>

#define NN 1000000
#define FF 5
#define EE 32000000
#define BBITS 10
#define BWIDTH 1024
#define NBUCK 977          /* ((NN-1)>>BBITS)+1 */
#define NBLK 512           /* edge-slice blocks for hist/scatter */
#define SLICE (EE / NBLK)  /* 62500 exactly */

// ============================ FAST PATH ============================

// Pass A: per-block histogram of dst buckets; also accumulate global totals.
__global__ __launch_bounds__(1024) void k_hist(const int* __restrict__ ei,
                                               unsigned* __restrict__ blockHist,
                                               unsigned* __restrict__ totals) {
    __shared__ unsigned h[NBUCK];
    int t = threadIdx.x, blk = blockIdx.x;
    for (int i = t; i < NBUCK; i += 1024) h[i] = 0u;
    __syncthreads();
    const int* dsts = ei + EE + (size_t)blk * SLICE;
    for (int i = t; i < SLICE; i += 1024)
        atomicAdd(&h[((unsigned)dsts[i]) >> BBITS], 1u);
    __syncthreads();
    for (int i = t; i < NBUCK; i += 1024) {
        unsigned c = h[i];
        blockHist[(size_t)i * NBLK + blk] = c;   // bucket-major layout
        if (c) atomicAdd(&totals[i], c);
    }
}

// Pass B1: exclusive scan over bucket totals -> bucket base offsets.
__global__ __launch_bounds__(1024) void k_base(const unsigned* __restrict__ totals,
                                               unsigned* __restrict__ base) {
    __shared__ unsigned s[1024];
    int t = threadIdx.x;
    unsigned v = (t < NBUCK) ? totals[t] : 0u;
    s[t] = v;
    __syncthreads();
    for (int off = 1; off < 1024; off <<= 1) {
        unsigned add = (t >= off) ? s[t - off] : 0u;
        __syncthreads();
        s[t] += add;
        __syncthreads();
    }
    if (t < NBUCK) base[t] = s[t] - v;   // exclusive
}

// Pass B2: per-bucket scan across blocks -> per-(block,bucket) write offsets.
__global__ __launch_bounds__(NBLK) void k_off(const unsigned* __restrict__ blockHist,
                                              const unsigned* __restrict__ base,
                                              unsigned* __restrict__ blockOff) {
    __shared__ unsigned s[NBLK];
    int b = blockIdx.x, t = threadIdx.x;
    unsigned v = blockHist[(size_t)b * NBLK + t];
    s[t] = v;
    __syncthreads();
    for (int off = 1; off < NBLK; off <<= 1) {
        unsigned add = (t >= off) ? s[t - off] : 0u;
        __syncthreads();
        s[t] += add;
        __syncthreads();
    }
    blockOff[(size_t)b * NBLK + t] = base[b] + s[t] - v;
}

// Pass C: scatter edges into bucket-contiguous binned array (plain writes only).
__global__ __launch_bounds__(1024) void k_scatter(const int* __restrict__ ei,
                                                  const unsigned* __restrict__ blockOff,
                                                  unsigned* __restrict__ binned) {
    __shared__ unsigned cnt[NBUCK];
    int t = threadIdx.x, blk = blockIdx.x;
    for (int i = t; i < NBUCK; i += 1024)
        cnt[i] = blockOff[(size_t)i * NBLK + blk];
    __syncthreads();
    const int* srcs = ei + (size_t)blk * SLICE;
    const int* dsts = ei + EE + (size_t)blk * SLICE;
    for (int i = t; i < SLICE; i += 1024) {
        unsigned s = (unsigned)srcs[i];
        unsigned d = (unsigned)dsts[i];
        unsigned pos = atomicAdd(&cnt[d >> BBITS], 1u);
        binned[pos] = (s << BBITS) | (d & (BWIDTH - 1));
    }
}

// degree (in-edges per node) from binned structure -> dis = rsqrt(deg+1)
__global__ __launch_bounds__(1024) void k_disb(const unsigned* __restrict__ binned,
                                               const unsigned* __restrict__ base,
                                               const unsigned* __restrict__ totals,
                                               float* __restrict__ dis) {
    __shared__ unsigned c[BWIDTH];
    int t = threadIdx.x, b = blockIdx.x;
    c[t] = 0u;
    __syncthreads();
    unsigned start = base[b], len = totals[b];
    for (unsigned i = t; i < len; i += 1024)
        atomicAdd(&c[binned[start + i] & (BWIDTH - 1)], 1u);
    __syncthreads();
    int node = (b << BBITS) + t;
    if (node < NN) dis[node] = rsqrtf((float)(c[t] + 1u));
}

// y = (x @ W1) * dis, rows padded to 8 floats (aligned float4 gathers later)
__global__ void k_y1p(const float* __restrict__ x, const float* __restrict__ dis,
                      const float* __restrict__ W, float* __restrict__ y) {
    int i = blockIdx.x * blockDim.x + threadIdx.x;
    if (i >= NN) return;
    float xi[FF];
#pragma unroll
    for (int f = 0; f < FF; f++) xi[f] = x[(size_t)i * FF + f];
    float d = dis[i];
    float o[FF];
#pragma unroll
    for (int q = 0; q < FF; q++) {
        float acc = 0.f;
#pragma unroll
        for (int k = 0; k < FF; k++) acc += xi[k] * W[k * FF + q];
        o[q] = acc * d;
    }
    float4* dst = (float4*)(y + (size_t)i * 8);
    dst[0] = make_float4(o[0], o[1], o[2], o[3]);
    dst[1] = make_float4(o[4], 0.f, 0.f, 0.f);
}

// layer-1 aggregate + fused epilogue: y2 = (relu((agg+y_self)*dis + b1) @ W2) * dis
__global__ __launch_bounds__(1024) void k_agg1(const unsigned* __restrict__ binned,
                                               const unsigned* __restrict__ base,
                                               const unsigned* __restrict__ totals,
                                               const float* __restrict__ y,
                                               const float* __restrict__ dis,
                                               const float* __restrict__ b1,
                                               const float* __restrict__ W2,
                                               float* __restrict__ y2) {
    __shared__ float acc[BWIDTH * FF];
    int t = threadIdx.x, b = blockIdx.x;
#pragma unroll
    for (int i = 0; i < FF; i++) acc[i * 1024 + t] = 0.f;
    __syncthreads();
    unsigned start = base[b], len = totals[b];
    for (unsigned i = t; i < len; i += 1024) {
        unsigned p = binned[start + i];
        const float* yr = y + (size_t)(p >> BBITS) * 8;
        float4 v4 = *(const float4*)yr;
        float v5 = yr[4];
        float* a = acc + (p & (BWIDTH - 1)) * FF;
        atomicAdd(a + 0, v4.x);
        atomicAdd(a + 1, v4.y);
        atomicAdd(a + 2, v4.z);
        atomicAdd(a + 3, v4.w);
        atomicAdd(a + 4, v5);
    }
    __syncthreads();
    int node = (b << BBITS) + t;
    if (node >= NN) return;
    float d = dis[node];
    const float* yr = y + (size_t)node * 8;
    float h[FF];
#pragma unroll
    for (int f = 0; f < FF; f++)
        h[f] = fmaxf((acc[t * FF + f] + yr[f]) * d + b1[f], 0.f);
    float o[FF];
#pragma unroll
    for (int q = 0; q < FF; q++) {
        float s = 0.f;
#pragma unroll
        for (int k = 0; k < FF; k++) s += h[k] * W2[k * FF + q];
        o[q] = s * d;
    }
    float4* dst = (float4*)(y2 + (size_t)node * 8);
    dst[0] = make_float4(o[0], o[1], o[2], o[3]);
    dst[1] = make_float4(o[4], 0.f, 0.f, 0.f);
}

// layer-2 aggregate + fused head: out = relu((agg+y2_self)*dis + b2) @ Wl + bl
__global__ __launch_bounds__(1024) void k_agg2(const unsigned* __restrict__ binned,
                                               const unsigned* __restrict__ base,
                                               const unsigned* __restrict__ totals,
                                               const float* __restrict__ y2,
                                               const float* __restrict__ dis,
                                               const float* __restrict__ b2,
                                               const float* __restrict__ Wl,
                                               const float* __restrict__ bl,
                                               float* __restrict__ out) {
    __shared__ float acc[BWIDTH * FF];
    int t = threadIdx.x, b = blockIdx.x;
#pragma unroll
    for (int i = 0; i < FF; i++) acc[i * 1024 + t] = 0.f;
    __syncthreads();
    unsigned start = base[b], len = totals[b];
    for (unsigned i = t; i < len; i += 1024) {
        unsigned p = binned[start + i];
        const float* yr = y2 + (size_t)(p >> BBITS) * 8;
        float4 v4 = *(const float4*)yr;
        float v5 = yr[4];
        float* a = acc + (p & (BWIDTH - 1)) * FF;
        atomicAdd(a + 0, v4.x);
        atomicAdd(a + 1, v4.y);
        atomicAdd(a + 2, v4.z);
        atomicAdd(a + 3, v4.w);
        atomicAdd(a + 4, v5);
    }
    __syncthreads();
    int node = (b << BBITS) + t;
    if (node >= NN) return;
    float d = dis[node];
    const float* yr = y2 + (size_t)node * 8;
    float v = bl[0];
#pragma unroll
    for (int f = 0; f < FF; f++)
        v += fmaxf((acc[t * FF + f] + yr[f]) * d + b2[f], 0.f) * Wl[f];
    out[node] = v;
}

// ===================== FALLBACK (round-1 atomic path) =====================

__global__ void k_deg(const int* __restrict__ ei, int E, unsigned int* __restrict__ deg) {
    int t = blockIdx.x * blockDim.x + threadIdx.x;
    int stride = gridDim.x * blockDim.x;
    for (int e = t; e < E; e += stride) atomicAdd(&deg[ei[E + e]], 1u);
}
__global__ void k_dis(const unsigned int* __restrict__ deg, float* __restrict__ dis) {
    int i = blockIdx.x * blockDim.x + threadIdx.x;
    if (i < NN) dis[i] = rsqrtf((float)(deg[i] + 1u));
}
__global__ void k_y1(const float* __restrict__ x, const float* __restrict__ dis,
                     const float* __restrict__ W, float* __restrict__ y, float* __restrict__ z) {
    int i = blockIdx.x * blockDim.x + threadIdx.x;
    if (i >= NN) return;
    float xi[FF];
#pragma unroll
    for (int f = 0; f < FF; f++) xi[f] = x[i * FF + f];
    float d = dis[i];
#pragma unroll
    for (int o = 0; o < FF; o++) {
        float acc = 0.f;
#pragma unroll
        for (int k = 0; k < FF; k++) acc += xi[k] * W[k * FF + o];
        acc *= d;
        y[i * FF + o] = acc;
        z[i * FF + o] = acc;
    }
}
__global__ void k_edge(const int* __restrict__ ei, int E,
                       const float* __restrict__ y, float* __restrict__ z) {
    int t = blockIdx.x * blockDim.x + threadIdx.x;
    int stride = gridDim.x * blockDim.x;
    for (int e = t; e < E; e += stride) {
        int s = ei[e], d = ei[E + e];
        const float* ys = y + (size_t)s * FF;
        float* zd = z + (size_t)d * FF;
#pragma unroll
        for (int f = 0; f < FF; f++) atomicAdd(&zd[f], ys[f]);
    }
}
__global__ void k_mid(const float* __restrict__ z1, const float* __restrict__ dis,
                      const float* __restrict__ b1, const float* __restrict__ W2,
                      float* __restrict__ y2, float* __restrict__ z2) {
    int i = blockIdx.x * blockDim.x + threadIdx.x;
    if (i >= NN) return;
    float d = dis[i];
    float h[FF];
#pragma unroll
    for (int f = 0; f < FF; f++) h[f] = fmaxf(z1[i * FF + f] * d + b1[f], 0.f);
#pragma unroll
    for (int o = 0; o < FF; o++) {
        float acc = 0.f;
#pragma unroll
        for (int k = 0; k < FF; k++) acc += h[k] * W2[k * FF + o];
        acc *= d;
        y2[i * FF + o] = acc;
        z2[i * FF + o] = acc;
    }
}
__global__ void k_final(const float* __restrict__ z2, const float* __restrict__ dis,
                        const float* __restrict__ b2, const float* __restrict__ Wl,
                        const float* __restrict__ bl, float* __restrict__ out) {
    int i = blockIdx.x * blockDim.x + threadIdx.x;
    if (i >= NN) return;
    float d = dis[i];
    float acc = bl[0];
#pragma unroll
    for (int f = 0; f < FF; f++)
        acc += fmaxf(z2[i * FF + f] * d + b2[f], 0.f) * Wl[f];
    out[i] = acc;
}

// ================================ launch ================================

extern "C" void kernel_launch(void* const* d_in, const int* in_sizes, int n_in,
                              void* d_out, int out_size, void* d_ws, size_t ws_size,
                              hipStream_t stream) {
    const float* x  = (const float*)d_in[0];
    const int*   ei = (const int*)d_in[1];
    const float* W1 = (const float*)d_in[2];
    const float* b1 = (const float*)d_in[3];
    const float* W2 = (const float*)d_in[4];
    const float* b2 = (const float*)d_in[5];
    const float* Wl = (const float*)d_in[6];
    const float* bl = (const float*)d_in[7];
    float* out = (float*)d_out;
    const int E = in_sizes[1] / 2;

    char* ws = (char*)d_ws;
    const size_t REQUIRED = 208ull << 20;

    if (E == EE && ws_size >= REQUIRED) {
        // -------- fast binned path --------
        unsigned* totals    = (unsigned*)(ws);
        unsigned* base      = (unsigned*)(ws + (4 << 10));
        unsigned* blockHist = (unsigned*)(ws + (8 << 10));
        unsigned* blockOff  = (unsigned*)(ws + (8 << 10) + (2 << 20));
        float*    dis       = (float*)(ws + (8ull << 20));
        float*    y         = (float*)(ws + (16ull << 20));   // 1M x 8 f32
        float*    y2        = (float*)(ws + (48ull << 20));   // 1M x 8 f32
        unsigned* binned    = (unsigned*)(ws + (80ull << 20)); // 32M u32

        hipMemsetAsync(totals, 0, NBUCK * sizeof(unsigned), stream);

        const int NT = 256, NB = (NN + NT - 1) / NT;
        k_hist   <<<NBLK, 1024, 0, stream>>>(ei, blockHist, totals);
        k_base   <<<1, 1024, 0, stream>>>(totals, base);
        k_off    <<<NBUCK, NBLK, 0, stream>>>(blockHist, base, blockOff);
        k_scatter<<<NBLK, 1024, 0, stream>>>(ei, blockOff, binned);
        k_disb   <<<NBUCK, 1024, 0, stream>>>(binned, base, totals, dis);
        k_y1p    <<<NB, NT, 0, stream>>>(x, dis, W1, y);
        k_agg1   <<<NBUCK, 1024, 0, stream>>>(binned, base, totals, y, dis, b1, W2, y2);
        k_agg2   <<<NBUCK, 1024, 0, stream>>>(binned, base, totals, y2, dis, b2, Wl, bl, out);
    } else {
        // -------- fallback: round-1 global-atomic path (needs 68 MB) --------
        unsigned int* deg = (unsigned int*)(ws);
        float* dis = (float*)(ws + (size_t)4 * 1024 * 1024);
        float* A   = (float*)(ws + (size_t)8 * 1024 * 1024);
        float* B   = (float*)(ws + (size_t)28 * 1024 * 1024);
        float* C   = (float*)(ws + (size_t)48 * 1024 * 1024);

        hipMemsetAsync(deg, 0, (size_t)NN * sizeof(unsigned int), stream);

        const int ET = 256, EB = 2048;
        const int NT = 256, NB = (NN + NT - 1) / NT;
        k_deg  <<<EB, ET, 0, stream>>>(ei, E, deg);
        k_dis  <<<NB, NT, 0, stream>>>(deg, dis);
        k_y1   <<<NB, NT, 0, stream>>>(x, dis, W1, A, B);
        k_edge <<<EB, ET, 0, stream>>>(ei, E, A, B);
        k_mid  <<<NB, NT, 0, stream>>>(B, dis, b1, W2, A, C);
        k_edge <<<EB, ET, 0, stream>>>(ei, E, A, C);
        k_final<<<NB, NT, 0, stream>>>(C, dis, b2, Wl, bl, out);
    }
}

// Round 3
// 2199.564 us; speedup vs baseline: 7.6912x; 1.0964x over previous
//
#include <hip/hip_runtime.h>
#include <math.h>

#define NN 1000000
#define FF 5
#define EE 32000000
#define BBITS 10
#define BWIDTH 1024
#define NBUCK 977          /* ((NN-1)>>BBITS)+1 */
#define NBLK 512           /* edge-slice blocks for hist/scatter */
#define SLICE (EE / NBLK)  /* 62500 exactly */

typedef unsigned u32;
typedef u32 u32x4 __attribute__((ext_vector_type(4)));
typedef int i32x4 __attribute__((ext_vector_type(4)));

// ============================ FAST PATH ============================

// Pass A: per-block histogram of dst buckets; also accumulate global totals.
__global__ __launch_bounds__(1024) void k_hist(const int* __restrict__ ei,
                                               unsigned* __restrict__ blockHist,
                                               unsigned* __restrict__ totals) {
    __shared__ unsigned h[NBUCK];
    int t = threadIdx.x, blk = blockIdx.x;
    for (int i = t; i < NBUCK; i += 1024) h[i] = 0u;
    __syncthreads();
    const i32x4* dsts = (const i32x4*)(ei + EE + (size_t)blk * SLICE);
    for (int i = t; i < SLICE / 4; i += 1024) {
        i32x4 d = __builtin_nontemporal_load(dsts + i);
        atomicAdd(&h[((unsigned)d.x) >> BBITS], 1u);
        atomicAdd(&h[((unsigned)d.y) >> BBITS], 1u);
        atomicAdd(&h[((unsigned)d.z) >> BBITS], 1u);
        atomicAdd(&h[((unsigned)d.w) >> BBITS], 1u);
    }
    __syncthreads();
    for (int i = t; i < NBUCK; i += 1024) {
        unsigned c = h[i];
        blockHist[(size_t)i * NBLK + blk] = c;   // bucket-major layout
        if (c) atomicAdd(&totals[i], c);
    }
}

// Pass B1: exclusive scan over PADDED bucket totals -> bucket base offsets.
// Segments padded to multiples of 8 so agg kernels can batch-load uint4 pairs.
__global__ __launch_bounds__(1024) void k_base(const unsigned* __restrict__ totals,
                                               unsigned* __restrict__ base) {
    __shared__ unsigned s[1024];
    int t = threadIdx.x;
    unsigned v = (t < NBUCK) ? ((totals[t] + 7u) & ~7u) : 0u;
    s[t] = v;
    __syncthreads();
    for (int off = 1; off < 1024; off <<= 1) {
        unsigned add = (t >= off) ? s[t - off] : 0u;
        __syncthreads();
        s[t] += add;
        __syncthreads();
    }
    if (t < NBUCK) base[t] = s[t] - v;   // exclusive (padded)
}

// Pass B2: per-bucket scan across blocks -> per-(block,bucket) write offsets.
__global__ __launch_bounds__(NBLK) void k_off(const unsigned* __restrict__ blockHist,
                                              const unsigned* __restrict__ base,
                                              unsigned* __restrict__ blockOff) {
    __shared__ unsigned s[NBLK];
    int b = blockIdx.x, t = threadIdx.x;
    unsigned v = blockHist[(size_t)b * NBLK + t];
    s[t] = v;
    __syncthreads();
    for (int off = 1; off < NBLK; off <<= 1) {
        unsigned add = (t >= off) ? s[t - off] : 0u;
        __syncthreads();
        s[t] += add;
        __syncthreads();
    }
    blockOff[(size_t)b * NBLK + t] = base[b] + s[t] - v;
}

// Pass C: scatter edges into bucket-contiguous binned array (plain writes only).
__global__ __launch_bounds__(1024) void k_scatter(const int* __restrict__ ei,
                                                  const unsigned* __restrict__ blockOff,
                                                  unsigned* __restrict__ binned) {
    __shared__ unsigned cnt[NBUCK];
    int t = threadIdx.x, blk = blockIdx.x;
    for (int i = t; i < NBUCK; i += 1024)
        cnt[i] = blockOff[(size_t)i * NBLK + blk];
    __syncthreads();
    const i32x4* srcs = (const i32x4*)(ei + (size_t)blk * SLICE);
    const i32x4* dsts = (const i32x4*)(ei + EE + (size_t)blk * SLICE);
    for (int i = t; i < SLICE / 4; i += 1024) {
        i32x4 s4 = __builtin_nontemporal_load(srcs + i);
        i32x4 d4 = __builtin_nontemporal_load(dsts + i);
#pragma unroll
        for (int j = 0; j < 4; j++) {
            unsigned s = (unsigned)((j == 0) ? s4.x : (j == 1) ? s4.y : (j == 2) ? s4.z : s4.w);
            unsigned d = (unsigned)((j == 0) ? d4.x : (j == 1) ? d4.y : (j == 2) ? d4.z : d4.w);
            unsigned pos = atomicAdd(&cnt[d >> BBITS], 1u);
            binned[pos] = (s << BBITS) | (d & (BWIDTH - 1));
        }
    }
}

// Pad each bucket segment to a multiple of 8 with sentinel edges (src=NN -> zero row).
__global__ __launch_bounds__(1024) void k_pad(const unsigned* __restrict__ totals,
                                              const unsigned* __restrict__ base,
                                              unsigned* __restrict__ binned) {
    int t = threadIdx.x;
    if (t >= NBUCK) return;
    unsigned len = totals[t];
    unsigned st = base[t] + len;
    unsigned en = base[t] + ((len + 7u) & ~7u);
    for (unsigned u = st; u < en; u++) binned[u] = ((unsigned)NN) << BBITS;
}

// Fused: per-node degree (from binned) -> dis = rsqrt(deg+1) -> y = (x@W1)*dis.
// y rows padded to 8 floats; row NN is all zeros (sentinel target).
__global__ __launch_bounds__(1024) void k_disy(const unsigned* __restrict__ binned,
                                               const unsigned* __restrict__ base,
                                               const unsigned* __restrict__ totals,
                                               const float* __restrict__ x,
                                               const float* __restrict__ W,
                                               float* __restrict__ dis,
                                               float* __restrict__ y) {
    __shared__ unsigned c[BWIDTH];
    int t = threadIdx.x, b = blockIdx.x;
    c[t] = 0u;
    __syncthreads();
    unsigned start = base[b], len = totals[b], lenp = (len + 7u) & ~7u;
    for (unsigned i = (unsigned)t * 8u; i < lenp; i += 8192u) {
        const u32x4* bp = (const u32x4*)(binned + start + i);
        u32x4 a = __builtin_nontemporal_load(bp);
        u32x4 d = __builtin_nontemporal_load(bp + 1);
        unsigned p[8] = {a.x, a.y, a.z, a.w, d.x, d.y, d.z, d.w};
#pragma unroll
        for (int j = 0; j < 8; j++)
            if ((p[j] >> BBITS) != (unsigned)NN)     // skip pad sentinels
                atomicAdd(&c[p[j] & (BWIDTH - 1)], 1u);
    }
    __syncthreads();
    int node = (b << BBITS) + t;
    if (node > NN) return;
    float4* dst = (float4*)(y + (size_t)node * 8);
    if (node == NN) {                                 // sentinel zero row
        dst[0] = make_float4(0.f, 0.f, 0.f, 0.f);
        dst[1] = make_float4(0.f, 0.f, 0.f, 0.f);
        return;
    }
    float d = rsqrtf((float)(c[t] + 1u));
    dis[node] = d;
    float xi[FF];
#pragma unroll
    for (int f = 0; f < FF; f++) xi[f] = x[(size_t)node * FF + f];
    float o[FF];
#pragma unroll
    for (int q = 0; q < FF; q++) {
        float acc = 0.f;
#pragma unroll
        for (int k = 0; k < FF; k++) acc += xi[k] * W[k * FF + q];
        o[q] = acc * d;
    }
    dst[0] = make_float4(o[0], o[1], o[2], o[3]);
    dst[1] = make_float4(o[4], 0.f, 0.f, 0.f);
}

// layer-1 aggregate + fused epilogue: y2 = (relu((agg+y_self)*dis + b1) @ W2) * dis
__global__ __launch_bounds__(1024) void k_agg1(const unsigned* __restrict__ binned,
                                               const unsigned* __restrict__ base,
                                               const unsigned* __restrict__ totals,
                                               const float* __restrict__ y,
                                               const float* __restrict__ dis,
                                               const float* __restrict__ b1,
                                               const float* __restrict__ W2,
                                               float* __restrict__ y2) {
    __shared__ float acc[BWIDTH * FF];
    int t = threadIdx.x, b = blockIdx.x;
#pragma unroll
    for (int i = 0; i < FF; i++) acc[i * 1024 + t] = 0.f;
    __syncthreads();
    unsigned start = base[b], len = totals[b], lenp = (len + 7u) & ~7u;
    for (unsigned i = (unsigned)t * 8u; i < lenp; i += 8192u) {
        const u32x4* bp = (const u32x4*)(binned + start + i);
        u32x4 qa = __builtin_nontemporal_load(bp);
        u32x4 qb = __builtin_nontemporal_load(bp + 1);
        unsigned p[8] = {qa.x, qa.y, qa.z, qa.w, qb.x, qb.y, qb.z, qb.w};
        float4 v4[8]; float v5[8];
#pragma unroll
        for (int j = 0; j < 8; j++) {               // 16 independent gathers in flight
            const float* yr = y + (size_t)(p[j] >> BBITS) * 8;
            v4[j] = *(const float4*)yr;
            v5[j] = yr[4];
        }
#pragma unroll
        for (int j = 0; j < 8; j++) {
            float* a = acc + (p[j] & (BWIDTH - 1)) * FF;
            atomicAdd(a + 0, v4[j].x);
            atomicAdd(a + 1, v4[j].y);
            atomicAdd(a + 2, v4[j].z);
            atomicAdd(a + 3, v4[j].w);
            atomicAdd(a + 4, v5[j]);
        }
    }
    __syncthreads();
    int node = (b << BBITS) + t;
    if (node > NN) return;
    float4* dst = (float4*)(y2 + (size_t)node * 8);
    if (node == NN) {                                // keep sentinel row zero
        dst[0] = make_float4(0.f, 0.f, 0.f, 0.f);
        dst[1] = make_float4(0.f, 0.f, 0.f, 0.f);
        return;
    }
    float d = dis[node];
    const float* yr = y + (size_t)node * 8;
    float h[FF];
#pragma unroll
    for (int f = 0; f < FF; f++)
        h[f] = fmaxf((acc[t * FF + f] + yr[f]) * d + b1[f], 0.f);
    float o[FF];
#pragma unroll
    for (int q = 0; q < FF; q++) {
        float s = 0.f;
#pragma unroll
        for (int k = 0; k < FF; k++) s += h[k] * W2[k * FF + q];
        o[q] = s * d;
    }
    dst[0] = make_float4(o[0], o[1], o[2], o[3]);
    dst[1] = make_float4(o[4], 0.f, 0.f, 0.f);
}

// layer-2 aggregate + fused head: out = relu((agg+y2_self)*dis + b2) @ Wl + bl
__global__ __launch_bounds__(1024) void k_agg2(const unsigned* __restrict__ binned,
                                               const unsigned* __restrict__ base,
                                               const unsigned* __restrict__ totals,
                                               const float* __restrict__ y2,
                                               const float* __restrict__ dis,
                                               const float* __restrict__ b2,
                                               const float* __restrict__ Wl,
                                               const float* __restrict__ bl,
                                               float* __restrict__ out) {
    __shared__ float acc[BWIDTH * FF];
    int t = threadIdx.x, b = blockIdx.x;
#pragma unroll
    for (int i = 0; i < FF; i++) acc[i * 1024 + t] = 0.f;
    __syncthreads();
    unsigned start = base[b], len = totals[b], lenp = (len + 7u) & ~7u;
    for (unsigned i = (unsigned)t * 8u; i < lenp; i += 8192u) {
        const u32x4* bp = (const u32x4*)(binned + start + i);
        u32x4 qa = __builtin_nontemporal_load(bp);
        u32x4 qb = __builtin_nontemporal_load(bp + 1);
        unsigned p[8] = {qa.x, qa.y, qa.z, qa.w, qb.x, qb.y, qb.z, qb.w};
        float4 v4[8]; float v5[8];
#pragma unroll
        for (int j = 0; j < 8; j++) {
            const float* yr = y2 + (size_t)(p[j] >> BBITS) * 8;
            v4[j] = *(const float4*)yr;
            v5[j] = yr[4];
        }
#pragma unroll
        for (int j = 0; j < 8; j++) {
            float* a = acc + (p[j] & (BWIDTH - 1)) * FF;
            atomicAdd(a + 0, v4[j].x);
            atomicAdd(a + 1, v4[j].y);
            atomicAdd(a + 2, v4[j].z);
            atomicAdd(a + 3, v4[j].w);
            atomicAdd(a + 4, v5[j]);
        }
    }
    __syncthreads();
    int node = (b << BBITS) + t;
    if (node >= NN) return;
    float d = dis[node];
    const float* yr = y2 + (size_t)node * 8;
    float v = bl[0];
#pragma unroll
    for (int f = 0; f < FF; f++)
        v += fmaxf((acc[t * FF + f] + yr[f]) * d + b2[f], 0.f) * Wl[f];
    out[node] = v;
}

// ===================== FALLBACK (round-1 atomic path) =====================

__global__ void k_deg(const int* __restrict__ ei, int E, unsigned int* __restrict__ deg) {
    int t = blockIdx.x * blockDim.x + threadIdx.x;
    int stride = gridDim.x * blockDim.x;
    for (int e = t; e < E; e += stride) atomicAdd(&deg[ei[E + e]], 1u);
}
__global__ void k_dis(const unsigned int* __restrict__ deg, float* __restrict__ dis) {
    int i = blockIdx.x * blockDim.x + threadIdx.x;
    if (i < NN) dis[i] = rsqrtf((float)(deg[i] + 1u));
}
__global__ void k_y1(const float* __restrict__ x, const float* __restrict__ dis,
                     const float* __restrict__ W, float* __restrict__ y, float* __restrict__ z) {
    int i = blockIdx.x * blockDim.x + threadIdx.x;
    if (i >= NN) return;
    float xi[FF];
#pragma unroll
    for (int f = 0; f < FF; f++) xi[f] = x[i * FF + f];
    float d = dis[i];
#pragma unroll
    for (int o = 0; o < FF; o++) {
        float acc = 0.f;
#pragma unroll
        for (int k = 0; k < FF; k++) acc += xi[k] * W[k * FF + o];
        acc *= d;
        y[i * FF + o] = acc;
        z[i * FF + o] = acc;
    }
}
__global__ void k_edge(const int* __restrict__ ei, int E,
                       const float* __restrict__ y, float* __restrict__ z) {
    int t = blockIdx.x * blockDim.x + threadIdx.x;
    int stride = gridDim.x * blockDim.x;
    for (int e = t; e < E; e += stride) {
        int s = ei[e], d = ei[E + e];
        const float* ys = y + (size_t)s * FF;
        float* zd = z + (size_t)d * FF;
#pragma unroll
        for (int f = 0; f < FF; f++) atomicAdd(&zd[f], ys[f]);
    }
}
__global__ void k_mid(const float* __restrict__ z1, const float* __restrict__ dis,
                      const float* __restrict__ b1, const float* __restrict__ W2,
                      float* __restrict__ y2, float* __restrict__ z2) {
    int i = blockIdx.x * blockDim.x + threadIdx.x;
    if (i >= NN) return;
    float d = dis[i];
    float h[FF];
#pragma unroll
    for (int f = 0; f < FF; f++) h[f] = fmaxf(z1[i * FF + f] * d + b1[f], 0.f);
#pragma unroll
    for (int o = 0; o < FF; o++) {
        float acc = 0.f;
#pragma unroll
        for (int k = 0; k < FF; k++) acc += h[k] * W2[k * FF + o];
        acc *= d;
        y2[i * FF + o] = acc;
        z2[i * FF + o] = acc;
    }
}
__global__ void k_final(const float* __restrict__ z2, const float* __restrict__ dis,
                        const float* __restrict__ b2, const float* __restrict__ Wl,
                        const float* __restrict__ bl, float* __restrict__ out) {
    int i = blockIdx.x * blockDim.x + threadIdx.x;
    if (i >= NN) return;
    float d = dis[i];
    float acc = bl[0];
#pragma unroll
    for (int f = 0; f < FF; f++)
        acc += fmaxf(z2[i * FF + f] * d + b2[f], 0.f) * Wl[f];
    out[i] = acc;
}

// ================================ launch ================================

extern "C" void kernel_launch(void* const* d_in, const int* in_sizes, int n_in,
                              void* d_out, int out_size, void* d_ws, size_t ws_size,
                              hipStream_t stream) {
    const float* x  = (const float*)d_in[0];
    const int*   ei = (const int*)d_in[1];
    const float* W1 = (const float*)d_in[2];
    const float* b1 = (const float*)d_in[3];
    const float* W2 = (const float*)d_in[4];
    const float* b2 = (const float*)d_in[5];
    const float* Wl = (const float*)d_in[6];
    const float* bl = (const float*)d_in[7];
    float* out = (float*)d_out;
    const int E = in_sizes[1] / 2;

    char* ws = (char*)d_ws;
    const size_t REQUIRED = 197ull << 20;

    if (E == EE && ws_size >= REQUIRED) {
        // -------- fast binned path --------
        // layout (MiB offsets): totals@0, base@4K, blockHist@8K, blockOff@8K+2M,
        // dis@6M, y@10M (NN+1 rows x 8 f32), y2@42M, binned@74M (32M + pads)
        unsigned* totals    = (unsigned*)(ws);
        unsigned* base      = (unsigned*)(ws + (4 << 10));
        unsigned* blockHist = (unsigned*)(ws + (8 << 10));
        unsigned* blockOff  = (unsigned*)(ws + (8 << 10) + (2 << 20));
        float*    dis       = (float*)(ws + (6ull << 20));
        float*    y         = (float*)(ws + (10ull << 20));
        float*    y2        = (float*)(ws + (42ull << 20));
        unsigned* binned    = (unsigned*)(ws + (74ull << 20));

        hipMemsetAsync(totals, 0, NBUCK * sizeof(unsigned), stream);

        k_hist   <<<NBLK, 1024, 0, stream>>>(ei, blockHist, totals);
        k_base   <<<1, 1024, 0, stream>>>(totals, base);
        k_off    <<<NBUCK, NBLK, 0, stream>>>(blockHist, base, blockOff);
        k_scatter<<<NBLK, 1024, 0, stream>>>(ei, blockOff, binned);
        k_pad    <<<1, 1024, 0, stream>>>(totals, base, binned);
        k_disy   <<<NBUCK, 1024, 0, stream>>>(binned, base, totals, x, W1, dis, y);
        k_agg1   <<<NBUCK, 1024, 0, stream>>>(binned, base, totals, y, dis, b1, W2, y2);
        k_agg2   <<<NBUCK, 1024, 0, stream>>>(binned, base, totals, y2, dis, b2, Wl, bl, out);
    } else {
        // -------- fallback: round-1 global-atomic path (needs 68 MB) --------
        unsigned int* deg = (unsigned int*)(ws);
        float* dis = (float*)(ws + (size_t)4 * 1024 * 1024);
        float* A   = (float*)(ws + (size_t)8 * 1024 * 1024);
        float* B   = (float*)(ws + (size_t)28 * 1024 * 1024);
        float* C   = (float*)(ws + (size_t)48 * 1024 * 1024);

        hipMemsetAsync(deg, 0, (size_t)NN * sizeof(unsigned int), stream);

        const int ET = 256, EB = 2048;
        const int NT = 256, NB = (NN + NT - 1) / NT;
        k_deg  <<<EB, ET, 0, stream>>>(ei, E, deg);
        k_dis  <<<NB, NT, 0, stream>>>(deg, dis);
        k_y1   <<<NB, NT, 0, stream>>>(x, dis, W1, A, B);
        k_edge <<<EB, ET, 0, stream>>>(ei, E, A, B);
        k_mid  <<<NB, NT, 0, stream>>>(B, dis, b1, W2, A, C);
        k_edge <<<EB, ET, 0, stream>>>(ei, E, A, C);
        k_final<<<NB, NT, 0, stream>>>(C, dis, b2, Wl, bl, out);
    }
}